// Round 8
// baseline (31419.415 us; speedup 1.0000x reference)
//
#include <hip/hip_runtime.h>

typedef _Float16 f16;
typedef _Float16 f16x2 __attribute__((ext_vector_type(2)));
typedef _Float16 f16x4 __attribute__((ext_vector_type(4)));
typedef _Float16 f16x8 __attribute__((ext_vector_type(8)));
typedef float f32x4 __attribute__((ext_vector_type(4)));
typedef unsigned int u32;
typedef unsigned int u32x4 __attribute__((ext_vector_type(4)));
typedef unsigned long long ull;

#define HD 512
#define T_TOT 16384
#define RING 128
#define NWG 32
#define NTH 512            // 8 waves, fully convergent main loop

// ---------------- ws layout (bytes) ----------------
static const size_t O_XC    = 0;                       // 16384*2048 f16  = 64MB
static const size_t O_W1    = 67108864;                // 2048*2048 f16   = 8MB
static const size_t O_WHH   = 75497472;                // 2048*512 f16    = 2MB
static const size_t O_W2    = 77594624;                // 2048*512 f16    = 2MB
static const size_t O_G     = 79691776;                // 16384*2048 f32  = 128MB
static const size_t O_PRING = 213909504;               // 128*256 ull     = 256KB

__device__ __forceinline__ float dot2f(f16x2 a, f16x2 b, float c) {
#if __has_builtin(__builtin_amdgcn_fdot2)
    return __builtin_amdgcn_fdot2(a, b, c, false);
#else
    return fmaf((float)a[0], (float)b[0], fmaf((float)a[1], (float)b[1], c));
#endif
}
__device__ __forceinline__ f16x2 bcf(u32 u) { return __builtin_bit_cast(f16x2, u); }

__device__ __forceinline__ float sigf(float x) { return 1.0f / (1.0f + __expf(-x)); }
__device__ __forceinline__ float tanhfast(float x) { return 1.0f - 2.0f / (__expf(2.0f * x) + 1.0f); }

// relaxed agent-scope (r2/r4-proven comm substrate; placement-independent)
__device__ __forceinline__ ull ld_a64(const ull* p) {
    return __hip_atomic_load(p, __ATOMIC_RELAXED, __HIP_MEMORY_SCOPE_AGENT);
}
__device__ __forceinline__ void st_a64(ull* p, ull v) {
    __hip_atomic_store(p, v, __ATOMIC_RELAXED, __HIP_MEMORY_SCOPE_AGENT);
}

// in-loop register pin: asm DEFINES the value each iteration -> downstream uses
// depend on the asm result, so the compiler cannot rematerialize the global
// load inside the loop; live range spans the backedge -> stays in VGPRs.
#define PIN8(A, B) asm volatile("" \
    : "+v"(A[B + 0]), "+v"(A[B + 1]), "+v"(A[B + 2]), "+v"(A[B + 3]), \
      "+v"(A[B + 4]), "+v"(A[B + 5]), "+v"(A[B + 6]), "+v"(A[B + 7]))

// ---------- convert x,hi -> XC f16 [t=s*64+b][k 0..2048) ----------
__global__ __launch_bounds__(256) void conv_xc(const float* __restrict__ x,
                                               const float* __restrict__ hi,
                                               f16* __restrict__ xc) {
    int gid = blockIdx.x * 256 + threadIdx.x;
    int t = gid >> 9;
    int k = (gid & 511) << 2;
    int b = t & 63, s = t >> 6;
    const float* src = (k < 1024) ? (x  + ((size_t)((b << 8) + s) << 10) + k)
                                  : (hi + ((size_t)((b << 8) + s) << 10) + (k - 1024));
    float4 v = *reinterpret_cast<const float4*>(src);
    f16x4 o = { (_Float16)v.x, (_Float16)v.y, (_Float16)v.z, (_Float16)v.w };
    *reinterpret_cast<f16x4*>(xc + ((size_t)t << 11) + k) = o;
}

// ---------- convert W_ih[:, :2048] -> W1 f16 row-major ----------
__global__ __launch_bounds__(256) void conv_w1(const float* __restrict__ wih,
                                               f16* __restrict__ w1) {
    int gid = blockIdx.x * 256 + threadIdx.x;
    int j = gid >> 9;
    int k = (gid & 511) << 2;
    float4 v = *reinterpret_cast<const float4*>(wih + (size_t)j * 2560 + k);
    f16x4 o = { (_Float16)v.x, (_Float16)v.y, (_Float16)v.z, (_Float16)v.w };
    *reinterpret_cast<f16x4*>(w1 + ((size_t)j << 11) + k) = o;
}

// ---------- convert W_hh and W_ih[:, 2048:2560] -> f16 ----------
__global__ __launch_bounds__(256) void conv_wc(const float* __restrict__ whh,
                                               const float* __restrict__ wih,
                                               f16* __restrict__ whhf,
                                               f16* __restrict__ w2f) {
    int gid = blockIdx.x * 256 + threadIdx.x;
    int j = gid >> 7;
    int k = (gid & 127) << 2;
    float4 a = *reinterpret_cast<const float4*>(whh + (size_t)j * 512 + k);
    f16x4 oa = { (_Float16)a.x, (_Float16)a.y, (_Float16)a.z, (_Float16)a.w };
    *reinterpret_cast<f16x4*>(whhf + ((size_t)j << 9) + k) = oa;
    float4 bv = *reinterpret_cast<const float4*>(wih + (size_t)j * 2560 + 2048 + k);
    f16x4 ob = { (_Float16)bv.x, (_Float16)bv.y, (_Float16)bv.z, (_Float16)bv.w };
    *reinterpret_cast<f16x4*>(w2f + ((size_t)j << 9) + k) = ob;
}

// ---------- G = XC @ W1^T + (b_ih+b_hh), f16 MFMA ----------
__global__ __launch_bounds__(256) void gemm_pre(const f16* __restrict__ XC,
                                                const f16* __restrict__ W1,
                                                const float* __restrict__ b_ih,
                                                const float* __restrict__ b_hh,
                                                float* __restrict__ G) {
    int w = threadIdx.x >> 6, l = threadIdx.x & 63;
    int R0 = blockIdx.y * 128 + (w >> 1) * 64;
    int C0 = blockIdx.x * 128 + (w & 1) * 64;
    int lr = l & 15, kb = l >> 4;
    f32x4 acc[4][4] = {};
    const f16* Abase = XC + (size_t)(R0 + lr) * 2048 + kb * 8;
    const f16* Bbase = W1 + (size_t)(C0 + lr) * 2048 + kb * 8;
    for (int kk = 0; kk < 2048; kk += 32) {
        f16x8 av[4], bv[4];
#pragma unroll
        for (int i = 0; i < 4; i++)
            av[i] = *reinterpret_cast<const f16x8*>(Abase + (size_t)(i * 16) * 2048 + kk);
#pragma unroll
        for (int i = 0; i < 4; i++)
            bv[i] = *reinterpret_cast<const f16x8*>(Bbase + (size_t)(i * 16) * 2048 + kk);
#pragma unroll
        for (int fr = 0; fr < 4; fr++)
#pragma unroll
            for (int fc = 0; fc < 4; fc++)
                acc[fr][fc] = __builtin_amdgcn_mfma_f32_16x16x32_f16(av[fr], bv[fc], acc[fr][fc], 0, 0, 0);
    }
#pragma unroll
    for (int fc = 0; fc < 4; fc++) {
        int col = C0 + fc * 16 + lr;
        float bias = b_ih[col] + b_hh[col];
#pragma unroll
        for (int fr = 0; fr < 4; fr++) {
#pragma unroll
            for (int r = 0; r < 4; r++) {
                int row = R0 + fr * 16 + kb * 4 + r;
                G[(size_t)row * 2048 + col] = acc[fr][fc][r] + bias;
            }
        }
    }
}

// ---------- sequential chain: 32 WGs x 512 threads, convergent, weights pinned ----------
// Wave wv (0..7): gate g=wv&3, unit-half uh=wv>>2 -> 8 rows; lane l: k-slice
// h[8l..8l+8).  Ring ull = [tag32 | h(2j+1) | h(2j)], every ull tagged (t+1).
// Publish = 8 relaxed stores; poll = speculative ld4 + per-lane retry.
// All 8 waves redundantly run the cell; weights pinned in-loop via PIN8.
__global__ __launch_bounds__(NTH, 1) void lstm_chain(const float* __restrict__ G,
                                                     const f16* __restrict__ Whhf,
                                                     const f16* __restrict__ W2f,
                                                     ull* __restrict__ ring,
                                                     float* __restrict__ out) {
    const int wg = blockIdx.x;
    const int tid = threadIdx.x;
    const int wv = tid >> 6, l = tid & 63;
    const int g = wv & 3, uh = wv >> 2;
    const int rr = ((l & 1) << 2) | (l & 2) | ((l >> 2) & 1);   // bitrev3(l&7)
    const int row0 = g * 512 + wg * 16 + uh * 8;
    const int growD = row0 + rr;

    __shared__ u32 hist[64][256];                 // 64KB h history, slot = t mod 64
    __shared__ __align__(16) float part[2][16][4];// [buf][unit][gate]

    for (int i = tid; i < 4096; i += NTH)
        reinterpret_cast<u32x4*>(hist)[i] = (u32x4){0u, 0u, 0u, 0u};

    // ---- weights: 8 rows x 4 dwords x 2 matrices, loaded once ----
    u32 wu1[32], wu2[32];
#pragma unroll
    for (int r = 0; r < 8; r++) {
        u32x4 a = __builtin_bit_cast(u32x4,
            *reinterpret_cast<const f16x8*>(Whhf + (size_t)(row0 + r) * 512 + 8 * l));
        u32x4 b = __builtin_bit_cast(u32x4,
            *reinterpret_cast<const f16x8*>(W2f + (size_t)(row0 + r) * 512 + 8 * l));
        wu1[r * 4 + 0] = a.x; wu1[r * 4 + 1] = a.y; wu1[r * 4 + 2] = a.z; wu1[r * 4 + 3] = a.w;
        wu2[r * 4 + 0] = b.x; wu2[r * 4 + 1] = b.y; wu2[r * 4 + 2] = b.z; wu2[r * 4 + 3] = b.w;
    }

    float cst = 0.0f;
    float gv = (l < 8) ? G[growD] : 0.0f;          // G[t=0] for this lane's row
    __syncthreads();

    for (int t = 0; t < T_TOT; t++) {
        const int buf = t & 1;

        // ---- pin all 64 weight dwords: defeats load rematerialization ----
        PIN8(wu1, 0); PIN8(wu1, 8); PIN8(wu1, 16); PIN8(wu1, 24);
        PIN8(wu2, 0); PIN8(wu2, 8); PIN8(wu2, 16); PIN8(wu2, 24);

        // ---- phase A: W2 . h[t-64] from LDS (slot t%64) ----
        u32x4 hv = *reinterpret_cast<const u32x4*>(&hist[t & 63][4 * l]);
        float ac[8] = {0.f, 0.f, 0.f, 0.f, 0.f, 0.f, 0.f, 0.f};
        {
            f16x2 h0 = bcf(hv.x), h1 = bcf(hv.y), h2 = bcf(hv.z), h3 = bcf(hv.w);
#pragma unroll
            for (int r = 0; r < 8; r++) {
                ac[r] = dot2f(bcf(wu2[r * 4 + 0]), h0, ac[r]);
                ac[r] = dot2f(bcf(wu2[r * 4 + 1]), h1, ac[r]);
                ac[r] = dot2f(bcf(wu2[r * 4 + 2]), h2, ac[r]);
                ac[r] = dot2f(bcf(wu2[r * 4 + 3]), h3, ac[r]);
            }
        }

        // ---- poll h[t-1]: speculative tagged ld4, per-lane retry ----
        const ull* pB = ring + (size_t)((t - 1) & (RING - 1)) * 256 + 4 * l;
        const u32 want = (u32)t;
        ull b0 = ld_a64(pB + 0), b1 = ld_a64(pB + 1);
        ull b2 = ld_a64(pB + 2), b3 = ld_a64(pB + 3);
        while ((((u32)(b0 >> 32) ^ want) | ((u32)(b1 >> 32) ^ want) |
                ((u32)(b2 >> 32) ^ want) | ((u32)(b3 >> 32) ^ want)) != 0u) {
            b0 = ld_a64(pB + 0); b1 = ld_a64(pB + 1);
            b2 = ld_a64(pB + 2); b3 = ld_a64(pB + 3);
        }

        // ---- issue G(t+1) load early (consumed next iteration) ----
        int tn = (t + 1 < T_TOT) ? t + 1 : t;
        float gnext = (l < 8) ? G[(size_t)tn * 2048 + growD] : 0.0f;

        // wave 0 records h(t-1) into hist (read at step t+63's phase A)
        if (wv == 0)
            *reinterpret_cast<u32x4*>(&hist[(t - 1) & 63][4 * l]) =
                (u32x4){(u32)b0, (u32)b1, (u32)b2, (u32)b3};

        // ---- phase B: Whh . h[t-1] ----
        {
            f16x2 h0 = bcf((u32)b0), h1 = bcf((u32)b1), h2 = bcf((u32)b2), h3 = bcf((u32)b3);
#pragma unroll
            for (int r = 0; r < 8; r++) {
                ac[r] = dot2f(bcf(wu1[r * 4 + 0]), h0, ac[r]);
                ac[r] = dot2f(bcf(wu1[r * 4 + 1]), h1, ac[r]);
                ac[r] = dot2f(bcf(wu1[r * 4 + 2]), h2, ac[r]);
                ac[r] = dot2f(bcf(wu1[r * 4 + 3]), h3, ac[r]);
            }
        }

        // ---- reduce 8 rows x 64 lanes -> lanes<8 hold row bitrev3(l) ----
        const bool s0 = l & 1, s1 = l & 2, s2 = l & 4;
        float b4_0 = (s0 ? ac[4] : ac[0]) + __shfl_xor((s0 ? ac[0] : ac[4]), 1);
        float b4_1 = (s0 ? ac[5] : ac[1]) + __shfl_xor((s0 ? ac[1] : ac[5]), 1);
        float b4_2 = (s0 ? ac[6] : ac[2]) + __shfl_xor((s0 ? ac[2] : ac[6]), 1);
        float b4_3 = (s0 ? ac[7] : ac[3]) + __shfl_xor((s0 ? ac[3] : ac[7]), 1);
        float c2_0 = (s1 ? b4_2 : b4_0) + __shfl_xor((s1 ? b4_0 : b4_2), 2);
        float c2_1 = (s1 ? b4_3 : b4_1) + __shfl_xor((s1 ? b4_1 : b4_3), 2);
        float d    = (s2 ? c2_1 : c2_0) + __shfl_xor((s2 ? c2_0 : c2_1), 4);
        d += __shfl_xor(d, 8);
        d += __shfl_xor(d, 16);
        d += __shfl_xor(d, 32);
        if (l < 8)
            part[buf][uh * 8 + rr][g] = d + gv;
        gv = gnext;
        __syncthreads();

        // ---- cell: ALL waves, convergent (identical inputs -> identical state) ----
        const int u = l & 15;
        float4 pg = *reinterpret_cast<const float4*>(part[buf][u]);
        float fi = sigf(pg.x), ff = sigf(pg.y);
        float fgg = tanhfast(pg.z), fo = sigf(pg.w);
        cst = ff * cst + fi * fgg;
        float h = fo * tanhfast(cst);

        // pack 16 f16 -> 8 tagged ulls (convergent shfls)
        u32 hb = (u32)__builtin_bit_cast(unsigned short, (f16)h);
        u32 plo = (u32)__shfl((int)hb, 2 * (l & 7));
        u32 phi = (u32)__shfl((int)hb, 2 * (l & 7) + 1);
        ull pv = (ull)(plo & 0xffffu) | ((ull)(phi & 0xffffu) << 16) |
                 ((ull)(u32)(t + 1) << 32);
        if (wv == 0 && l < 8)
            st_a64(ring + (size_t)(t & (RING - 1)) * 256 + wg * 8 + l, pv);
        if (wv == 1 && l < 16) {
            int b = t & 63, s = t >> 6;
            out[((size_t)((b << 8) + s)) * 512 + wg * 16 + l] = h;
        }
    }
}

extern "C" void kernel_launch(void* const* d_in, const int* in_sizes, int n_in,
                              void* d_out, int out_size, void* d_ws, size_t ws_size,
                              hipStream_t stream) {
    const float* x    = (const float*)d_in[0];
    const float* hi   = (const float*)d_in[1];
    const float* W_ih = (const float*)d_in[2];
    const float* W_hh = (const float*)d_in[3];
    const float* b_ih = (const float*)d_in[4];
    const float* b_hh = (const float*)d_in[5];

    char* ws = (char*)d_ws;
    f16*   XCf   = (f16*)(ws + O_XC);
    f16*   W1f   = (f16*)(ws + O_W1);
    f16*   Whhf  = (f16*)(ws + O_WHH);
    f16*   W2f   = (f16*)(ws + O_W2);
    float* G     = (float*)(ws + O_G);
    ull*   ring  = (ull*)(ws + O_PRING);

    // zero ring every launch: tags=0 (t=0's wanted gen), h=0 (initial state)
    hipMemsetAsync(ring, 0, (size_t)RING * 256 * sizeof(ull), stream);

    conv_xc<<<32768, 256, 0, stream>>>(x, hi, XCf);
    conv_w1<<<4096, 256, 0, stream>>>(W_ih, W1f);
    conv_wc<<<1024, 256, 0, stream>>>(W_hh, W_ih, Whhf, W2f);
    gemm_pre<<<dim3(16, 128), 256, 0, stream>>>(XCf, W1f, b_ih, b_hh, G);
    lstm_chain<<<NWG, NTH, 0, stream>>>(G, Whhf, W2f, ring, (float*)d_out);
}

// Round 9
// 30304.178 us; speedup vs baseline: 1.0368x; 1.0368x over previous
//
#include <hip/hip_runtime.h>

typedef _Float16 f16;
typedef _Float16 f16x2 __attribute__((ext_vector_type(2)));
typedef _Float16 f16x4 __attribute__((ext_vector_type(4)));
typedef _Float16 f16x8 __attribute__((ext_vector_type(8)));
typedef float f32x4 __attribute__((ext_vector_type(4)));
typedef unsigned int u32;
typedef unsigned int u32x4 __attribute__((ext_vector_type(4)));
typedef unsigned long long ull;

#define HD 512
#define T_TOT 16384
#define RING 128
#define NWG 32
#define NTH 512            // 8 waves, fully convergent main loop

// ---------------- ws layout (bytes) ----------------
static const size_t O_XC    = 0;                       // 16384*2048 f16  = 64MB
static const size_t O_W1    = 67108864;                // 2048*2048 f16   = 8MB
static const size_t O_WHH   = 75497472;                // 2048*512 f16    = 2MB
static const size_t O_W2    = 77594624;                // 2048*512 f16    = 2MB
static const size_t O_G     = 79691776;                // 16384*2048 f32  = 128MB
static const size_t O_PRING = 213909504;               // 128*256 ull     = 256KB

__device__ __forceinline__ float dot2f(f16x2 a, f16x2 b, float c) {
#if __has_builtin(__builtin_amdgcn_fdot2)
    return __builtin_amdgcn_fdot2(a, b, c, false);
#else
    return fmaf((float)a[0], (float)b[0], fmaf((float)a[1], (float)b[1], c));
#endif
}
__device__ __forceinline__ f16x2 bcf(u32 u) { return __builtin_bit_cast(f16x2, u); }

__device__ __forceinline__ float sigf(float x) { return 1.0f / (1.0f + __expf(-x)); }
__device__ __forceinline__ float tanhfast(float x) { return 1.0f - 2.0f / (__expf(2.0f * x) + 1.0f); }

// relaxed agent-scope (r2/r4-proven comm substrate; placement-independent)
__device__ __forceinline__ ull ld_a64(const ull* p) {
    return __hip_atomic_load(p, __ATOMIC_RELAXED, __HIP_MEMORY_SCOPE_AGENT);
}
__device__ __forceinline__ void st_a64(ull* p, ull v) {
    __hip_atomic_store(p, v, __ATOMIC_RELAXED, __HIP_MEMORY_SCOPE_AGENT);
}

// ---------- convert x,hi -> XC f16 [t=s*64+b][k 0..2048) ----------
__global__ __launch_bounds__(256) void conv_xc(const float* __restrict__ x,
                                               const float* __restrict__ hi,
                                               f16* __restrict__ xc) {
    int gid = blockIdx.x * 256 + threadIdx.x;
    int t = gid >> 9;
    int k = (gid & 511) << 2;
    int b = t & 63, s = t >> 6;
    const float* src = (k < 1024) ? (x  + ((size_t)((b << 8) + s) << 10) + k)
                                  : (hi + ((size_t)((b << 8) + s) << 10) + (k - 1024));
    float4 v = *reinterpret_cast<const float4*>(src);
    f16x4 o = { (_Float16)v.x, (_Float16)v.y, (_Float16)v.z, (_Float16)v.w };
    *reinterpret_cast<f16x4*>(xc + ((size_t)t << 11) + k) = o;
}

// ---------- convert W_ih[:, :2048] -> W1 f16 row-major ----------
__global__ __launch_bounds__(256) void conv_w1(const float* __restrict__ wih,
                                               f16* __restrict__ w1) {
    int gid = blockIdx.x * 256 + threadIdx.x;
    int j = gid >> 9;
    int k = (gid & 511) << 2;
    float4 v = *reinterpret_cast<const float4*>(wih + (size_t)j * 2560 + k);
    f16x4 o = { (_Float16)v.x, (_Float16)v.y, (_Float16)v.z, (_Float16)v.w };
    *reinterpret_cast<f16x4*>(w1 + ((size_t)j << 11) + k) = o;
}

// ---------- convert W_hh and W_ih[:, 2048:2560] -> f16 ----------
__global__ __launch_bounds__(256) void conv_wc(const float* __restrict__ whh,
                                               const float* __restrict__ wih,
                                               f16* __restrict__ whhf,
                                               f16* __restrict__ w2f) {
    int gid = blockIdx.x * 256 + threadIdx.x;
    int j = gid >> 7;
    int k = (gid & 127) << 2;
    float4 a = *reinterpret_cast<const float4*>(whh + (size_t)j * 512 + k);
    f16x4 oa = { (_Float16)a.x, (_Float16)a.y, (_Float16)a.z, (_Float16)a.w };
    *reinterpret_cast<f16x4*>(whhf + ((size_t)j << 9) + k) = oa;
    float4 bv = *reinterpret_cast<const float4*>(wih + (size_t)j * 2560 + 2048 + k);
    f16x4 ob = { (_Float16)bv.x, (_Float16)bv.y, (_Float16)bv.z, (_Float16)bv.w };
    *reinterpret_cast<f16x4*>(w2f + ((size_t)j << 9) + k) = ob;
}

// ---------- G = XC @ W1^T + (b_ih+b_hh), f16 MFMA ----------
__global__ __launch_bounds__(256) void gemm_pre(const f16* __restrict__ XC,
                                                const f16* __restrict__ W1,
                                                const float* __restrict__ b_ih,
                                                const float* __restrict__ b_hh,
                                                float* __restrict__ G) {
    int w = threadIdx.x >> 6, l = threadIdx.x & 63;
    int R0 = blockIdx.y * 128 + (w >> 1) * 64;
    int C0 = blockIdx.x * 128 + (w & 1) * 64;
    int lr = l & 15, kb = l >> 4;
    f32x4 acc[4][4] = {};
    const f16* Abase = XC + (size_t)(R0 + lr) * 2048 + kb * 8;
    const f16* Bbase = W1 + (size_t)(C0 + lr) * 2048 + kb * 8;
    for (int kk = 0; kk < 2048; kk += 32) {
        f16x8 av[4], bv[4];
#pragma unroll
        for (int i = 0; i < 4; i++)
            av[i] = *reinterpret_cast<const f16x8*>(Abase + (size_t)(i * 16) * 2048 + kk);
#pragma unroll
        for (int i = 0; i < 4; i++)
            bv[i] = *reinterpret_cast<const f16x8*>(Bbase + (size_t)(i * 16) * 2048 + kk);
#pragma unroll
        for (int fr = 0; fr < 4; fr++)
#pragma unroll
            for (int fc = 0; fc < 4; fc++)
                acc[fr][fc] = __builtin_amdgcn_mfma_f32_16x16x32_f16(av[fr], bv[fc], acc[fr][fc], 0, 0, 0);
    }
#pragma unroll
    for (int fc = 0; fc < 4; fc++) {
        int col = C0 + fc * 16 + lr;
        float bias = b_ih[col] + b_hh[col];
#pragma unroll
        for (int fr = 0; fr < 4; fr++) {
#pragma unroll
            for (int r = 0; r < 4; r++) {
                int row = R0 + fr * 16 + kb * 4 + r;
                G[(size_t)row * 2048 + col] = acc[fr][fc][r] + bias;
            }
        }
    }
}

// ---------- sequential chain: 32 WGs x 512 threads, convergent ----------
// Weights are defined by ONE volatile asm block (16x global_load_dwordx4):
// volatile-asm results cannot be rematerialized -> the 64 dwords/thread must
// stay live in VGPRs across the whole loop (pressure ~100 << 512 budget).
// Wave wv: gate g=wv&3, unit-half uh=wv>>2 -> 8 rows; lane l: k-slice h[8l..+8).
// Ring ull = [tag32 | h(2j+1) | h(2j)], every ull tagged (t+1 at step t).
__global__ __launch_bounds__(NTH, 1) void lstm_chain(const float* __restrict__ G,
                                                     const f16* __restrict__ Whhf,
                                                     const f16* __restrict__ W2f,
                                                     ull* __restrict__ ring,
                                                     float* __restrict__ out) {
    const int wg = blockIdx.x;
    const int tid = threadIdx.x;
    const int wv = tid >> 6, l = tid & 63;
    const int g = wv & 3, uh = wv >> 2;
    const int rr = ((l & 1) << 2) | (l & 2) | ((l >> 2) & 1);   // bitrev3(l&7)
    const int row0 = g * 512 + wg * 16 + uh * 8;
    const int growD = row0 + rr;

    __shared__ u32 hist[64][256];                 // 64KB h history, slot = t mod 64
    __shared__ __align__(16) float part[2][16][4];// [buf][unit][gate]

    for (int i = tid; i < 4096; i += NTH)
        reinterpret_cast<u32x4*>(hist)[i] = (u32x4){0u, 0u, 0u, 0u};

    // ---- weights: 8 rows x 16B x 2 matrices via ONE volatile asm block ----
    u32x4 w1v[8], w2v[8];
    {
        const f16* p1a = Whhf + (size_t)row0 * 512 + 8 * l;   // rows 0..3 (1KB stride)
        const f16* p1b = p1a + 2048;                          // rows 4..7
        const f16* p2a = W2f + (size_t)row0 * 512 + 8 * l;
        const f16* p2b = p2a + 2048;
        asm volatile(
            "global_load_dwordx4 %0, %16, off\n\t"
            "global_load_dwordx4 %1, %16, off offset:1024\n\t"
            "global_load_dwordx4 %2, %16, off offset:2048\n\t"
            "global_load_dwordx4 %3, %16, off offset:3072\n\t"
            "global_load_dwordx4 %4, %17, off\n\t"
            "global_load_dwordx4 %5, %17, off offset:1024\n\t"
            "global_load_dwordx4 %6, %17, off offset:2048\n\t"
            "global_load_dwordx4 %7, %17, off offset:3072\n\t"
            "global_load_dwordx4 %8, %18, off\n\t"
            "global_load_dwordx4 %9, %18, off offset:1024\n\t"
            "global_load_dwordx4 %10, %18, off offset:2048\n\t"
            "global_load_dwordx4 %11, %18, off offset:3072\n\t"
            "global_load_dwordx4 %12, %19, off\n\t"
            "global_load_dwordx4 %13, %19, off offset:1024\n\t"
            "global_load_dwordx4 %14, %19, off offset:2048\n\t"
            "global_load_dwordx4 %15, %19, off offset:3072\n\t"
            "s_waitcnt vmcnt(0)"
            : "=&v"(w1v[0]), "=&v"(w1v[1]), "=&v"(w1v[2]), "=&v"(w1v[3]),
              "=&v"(w1v[4]), "=&v"(w1v[5]), "=&v"(w1v[6]), "=&v"(w1v[7]),
              "=&v"(w2v[0]), "=&v"(w2v[1]), "=&v"(w2v[2]), "=&v"(w2v[3]),
              "=&v"(w2v[4]), "=&v"(w2v[5]), "=&v"(w2v[6]), "=&v"(w2v[7])
            : "v"(p1a), "v"(p1b), "v"(p2a), "v"(p2b)
            : "memory");
    }

    float cst = 0.0f;
    float gv = (l < 8) ? G[growD] : 0.0f;          // G[t=0] for this lane's row
    __syncthreads();

    for (int t = 0; t < T_TOT; t++) {
        const int buf = t & 1;

        // ---- phase A: W2 . h[t-64] from LDS (slot t%64) ----
        u32x4 hv = *reinterpret_cast<const u32x4*>(&hist[t & 63][4 * l]);
        float ac[8] = {0.f, 0.f, 0.f, 0.f, 0.f, 0.f, 0.f, 0.f};
        {
            f16x2 h0 = bcf(hv.x), h1 = bcf(hv.y), h2 = bcf(hv.z), h3 = bcf(hv.w);
#pragma unroll
            for (int r = 0; r < 8; r++) {
                ac[r] = dot2f(bcf(w2v[r].x), h0, ac[r]);
                ac[r] = dot2f(bcf(w2v[r].y), h1, ac[r]);
                ac[r] = dot2f(bcf(w2v[r].z), h2, ac[r]);
                ac[r] = dot2f(bcf(w2v[r].w), h3, ac[r]);
            }
        }

        // ---- poll h[t-1]: speculative tagged ld4, per-lane retry ----
        const ull* pB = ring + (size_t)((t - 1) & (RING - 1)) * 256 + 4 * l;
        const u32 want = (u32)t;
        ull b0 = ld_a64(pB + 0), b1 = ld_a64(pB + 1);
        ull b2 = ld_a64(pB + 2), b3 = ld_a64(pB + 3);
        while ((((u32)(b0 >> 32) ^ want) | ((u32)(b1 >> 32) ^ want) |
                ((u32)(b2 >> 32) ^ want) | ((u32)(b3 >> 32) ^ want)) != 0u) {
            b0 = ld_a64(pB + 0); b1 = ld_a64(pB + 1);
            b2 = ld_a64(pB + 2); b3 = ld_a64(pB + 3);
        }

        // ---- issue G(t+1) load early (consumed next iteration) ----
        int tn = (t + 1 < T_TOT) ? t + 1 : t;
        float gnext = (l < 8) ? G[(size_t)tn * 2048 + growD] : 0.0f;

        // wave 0 records h(t-1) into hist (read at step t+63's phase A)
        if (wv == 0)
            *reinterpret_cast<u32x4*>(&hist[(t - 1) & 63][4 * l]) =
                (u32x4){(u32)b0, (u32)b1, (u32)b2, (u32)b3};

        // ---- phase B: Whh . h[t-1] ----
        {
            f16x2 h0 = bcf((u32)b0), h1 = bcf((u32)b1), h2 = bcf((u32)b2), h3 = bcf((u32)b3);
#pragma unroll
            for (int r = 0; r < 8; r++) {
                ac[r] = dot2f(bcf(w1v[r].x), h0, ac[r]);
                ac[r] = dot2f(bcf(w1v[r].y), h1, ac[r]);
                ac[r] = dot2f(bcf(w1v[r].z), h2, ac[r]);
                ac[r] = dot2f(bcf(w1v[r].w), h3, ac[r]);
            }
        }

        // ---- reduce 8 rows x 64 lanes -> lanes<8 hold row bitrev3(l) ----
        const bool s0 = l & 1, s1 = l & 2, s2 = l & 4;
        float b4_0 = (s0 ? ac[4] : ac[0]) + __shfl_xor((s0 ? ac[0] : ac[4]), 1);
        float b4_1 = (s0 ? ac[5] : ac[1]) + __shfl_xor((s0 ? ac[1] : ac[5]), 1);
        float b4_2 = (s0 ? ac[6] : ac[2]) + __shfl_xor((s0 ? ac[2] : ac[6]), 1);
        float b4_3 = (s0 ? ac[7] : ac[3]) + __shfl_xor((s0 ? ac[3] : ac[7]), 1);
        float c2_0 = (s1 ? b4_2 : b4_0) + __shfl_xor((s1 ? b4_0 : b4_2), 2);
        float c2_1 = (s1 ? b4_3 : b4_1) + __shfl_xor((s1 ? b4_1 : b4_3), 2);
        float d    = (s2 ? c2_1 : c2_0) + __shfl_xor((s2 ? c2_0 : c2_1), 4);
        d += __shfl_xor(d, 8);
        d += __shfl_xor(d, 16);
        d += __shfl_xor(d, 32);
        if (l < 8)
            part[buf][uh * 8 + rr][g] = d + gv;
        gv = gnext;
        __syncthreads();

        // ---- cell: ALL waves, convergent (identical inputs -> identical state) ----
        const int u = l & 15;
        float4 pg = *reinterpret_cast<const float4*>(part[buf][u]);
        float fi = sigf(pg.x), ff = sigf(pg.y);
        float fgg = tanhfast(pg.z), fo = sigf(pg.w);
        cst = ff * cst + fi * fgg;
        float h = fo * tanhfast(cst);

        // pack 16 f16 -> 8 tagged ulls (convergent shfls)
        u32 hb = (u32)__builtin_bit_cast(unsigned short, (f16)h);
        u32 plo = (u32)__shfl((int)hb, 2 * (l & 7));
        u32 phi = (u32)__shfl((int)hb, 2 * (l & 7) + 1);
        ull pv = (ull)(plo & 0xffffu) | ((ull)(phi & 0xffffu) << 16) |
                 ((ull)(u32)(t + 1) << 32);
        if (wv == 0 && l < 8)
            st_a64(ring + (size_t)(t & (RING - 1)) * 256 + wg * 8 + l, pv);
        if (wv == 1 && l < 16) {
            int b = t & 63, s = t >> 6;
            out[((size_t)((b << 8) + s)) * 512 + wg * 16 + l] = h;
        }
    }
}

extern "C" void kernel_launch(void* const* d_in, const int* in_sizes, int n_in,
                              void* d_out, int out_size, void* d_ws, size_t ws_size,
                              hipStream_t stream) {
    const float* x    = (const float*)d_in[0];
    const float* hi   = (const float*)d_in[1];
    const float* W_ih = (const float*)d_in[2];
    const float* W_hh = (const float*)d_in[3];
    const float* b_ih = (const float*)d_in[4];
    const float* b_hh = (const float*)d_in[5];

    char* ws = (char*)d_ws;
    f16*   XCf   = (f16*)(ws + O_XC);
    f16*   W1f   = (f16*)(ws + O_W1);
    f16*   Whhf  = (f16*)(ws + O_WHH);
    f16*   W2f   = (f16*)(ws + O_W2);
    float* G     = (float*)(ws + O_G);
    ull*   ring  = (ull*)(ws + O_PRING);

    // zero ring every launch: tags=0 (t=0's wanted gen), h=0 (initial state)
    hipMemsetAsync(ring, 0, (size_t)RING * 256 * sizeof(ull), stream);

    conv_xc<<<32768, 256, 0, stream>>>(x, hi, XCf);
    conv_w1<<<4096, 256, 0, stream>>>(W_ih, W1f);
    conv_wc<<<1024, 256, 0, stream>>>(W_hh, W_ih, Whhf, W2f);
    gemm_pre<<<dim3(16, 128), 256, 0, stream>>>(XCf, W1f, b_ih, b_hh, G);
    lstm_chain<<<NWG, NTH, 0, stream>>>(G, Whhf, W2f, ring, (float*)d_out);
}